// Round 4
// baseline (569.401 us; speedup 1.0000x reference)
//
#include <hip/hip_runtime.h>
#include <math.h>

#define N_NODES  50000
#define N_EDGES  800000
#define E_TOT    (N_EDGES + N_NODES)   // 850000 incl self loops
#define N_GRAPHS 128
#define IN_F     768
#define HID2     128
#define NHID     64

typedef __attribute__((ext_vector_type(8))) short bf16x8;
typedef __attribute__((ext_vector_type(4))) float f32x4;
typedef __attribute__((ext_vector_type(4))) unsigned short us4;

__device__ __forceinline__ float selu_f(float x) {
    const float alpha = 1.6732632423543772f;
    const float scale = 1.0507009873554805f;
    return scale * (x > 0.f ? x : alpha * (expf(x) - 1.f));
}

// round-to-nearest-even fp32 -> bf16
__device__ __forceinline__ unsigned short f2bf(float f) {
    unsigned u = __float_as_uint(f);
    u += 0x7FFFu + ((u >> 16) & 1u);
    return (unsigned short)(u >> 16);
}
__device__ __forceinline__ float bflo(unsigned q) { return __uint_as_float(q << 16); }
__device__ __forceinline__ float bfhi(unsigned q) { return __uint_as_float(q & 0xffff0000u); }

// ---------------- setup: zero deg + e-buffers, convert/transpose both weight matrices ----------------
__global__ void setup_k(const float* __restrict__ W1, const float* __restrict__ W2,
                        unsigned short* __restrict__ Wt1, unsigned short* __restrict__ Wt2,
                        unsigned* __restrict__ deg,
                        float* __restrict__ es1, float* __restrict__ ed1,
                        float* __restrict__ es2, float* __restrict__ ed2) {
    int i = blockIdx.x * blockDim.x + threadIdx.x;
    if (i < N_NODES) {
        deg[i] = 0u;
        es1[i] = 0.f; ed1[i] = 0.f;
        es2[i] = 0.f; ed2[i] = 0.f;
    }
    if (i < 128 * IN_F) {
        int n = i / IN_F, k = i - n * IN_F;
        Wt1[i] = f2bf(W1[(long)k * 128 + n]);
    }
    if (i < 128 * HID2) {
        int n = i >> 7, k = i & 127;
        Wt2[i] = f2bf(W2[(long)k * 128 + n]);
    }
}

// ---------------- GEMM: bf16 MFMA, M64/BK64, reg-prefetch; fused e_src/e_dst epilogue ----------------
// C is written QUARTER-MAJOR bf16: Cq[((col>>5)*N_NODES + row)*32 + (col&31)]
// so the gather pass reads a compact 3.2 MB table per feature-quarter (fits one XCD L2).
#define LDA2 72   // padded LDS row stride (bf16): 144 B; frag reads conflict-free
template<bool ABF16>
__global__ __launch_bounds__(256) void gemm_mfma(
        const void* __restrict__ Av, const unsigned short* __restrict__ Bt,
        unsigned short* __restrict__ Cq, int M, int K,
        const float* __restrict__ a_s, const float* __restrict__ a_d,
        float* __restrict__ es, float* __restrict__ ed) {
    __shared__ unsigned short As[64 * LDA2];    // 9.2 KB
    __shared__ unsigned short Bs[128 * LDA2];   // 18.4 KB
    const float* Af = (const float*)Av;
    const unsigned short* Ab = (const unsigned short*)Av;
    const int tid  = threadIdx.x;
    const int row0 = blockIdx.x * 64;
    const int w    = tid >> 6;
    const int lane = tid & 63;
    const int quad = lane >> 4;
    const int l16  = lane & 15;
    const int m_off = (w & 1) * 32;   // wave covers 32 rows
    const int n_off = (w >> 1) * 64;  // x 64 cols

    f32x4 acc[2][4];
#pragma unroll
    for (int mi = 0; mi < 2; mi++)
#pragma unroll
        for (int ni = 0; ni < 4; ni++)
            acc[mi][ni] = (f32x4){0.f, 0.f, 0.f, 0.f};

    float4 aR[4];
    bf16x8 aRb[2];
    bf16x8 bR[4];
    if (ABF16) {
#pragma unroll
        for (int i = 0; i < 2; i++) {
            int p = tid + i * 256;
            int r = p >> 3, c8 = p & 7;
            int gr = row0 + r;
            aRb[i] = (gr < M) ? *(const bf16x8*)&Ab[(long)gr * K + c8 * 8]
                              : (bf16x8){0,0,0,0,0,0,0,0};
        }
    } else {
#pragma unroll
        for (int i = 0; i < 4; i++) {
            int p = tid + i * 256;
            int r = p >> 4, c4 = p & 15;
            int gr = row0 + r;
            aR[i] = (gr < M) ? *(const float4*)&Af[(long)gr * K + c4 * 4]
                             : make_float4(0.f, 0.f, 0.f, 0.f);
        }
    }
#pragma unroll
    for (int i = 0; i < 4; i++) {
        int c = tid + i * 256;
        int n = c >> 3, koff = (c & 7) * 8;
        bR[i] = *(const bf16x8*)&Bt[(long)n * K + koff];
    }

    for (int k0 = 0; k0 < K; k0 += 64) {
        if (ABF16) {
#pragma unroll
            for (int i = 0; i < 2; i++) {
                int p = tid + i * 256;
                int r = p >> 3, c8 = p & 7;
                *(bf16x8*)&As[r * LDA2 + c8 * 8] = aRb[i];
            }
        } else {
#pragma unroll
            for (int i = 0; i < 4; i++) {
                int p = tid + i * 256;
                int r = p >> 4, c4 = p & 15;
                us4 o;
                o.x = f2bf(aR[i].x); o.y = f2bf(aR[i].y);
                o.z = f2bf(aR[i].z); o.w = f2bf(aR[i].w);
                *(us4*)&As[r * LDA2 + c4 * 4] = o;
            }
        }
#pragma unroll
        for (int i = 0; i < 4; i++) {
            int c = tid + i * 256;
            int n = c >> 3, koff = (c & 7) * 8;
            *(bf16x8*)&Bs[n * LDA2 + koff] = bR[i];
        }
        __syncthreads();

        if (k0 + 64 < K) {
            int k1 = k0 + 64;
            if (ABF16) {
#pragma unroll
                for (int i = 0; i < 2; i++) {
                    int p = tid + i * 256;
                    int r = p >> 3, c8 = p & 7;
                    int gr = row0 + r;
                    aRb[i] = (gr < M) ? *(const bf16x8*)&Ab[(long)gr * K + k1 + c8 * 8]
                                      : (bf16x8){0,0,0,0,0,0,0,0};
                }
            } else {
#pragma unroll
                for (int i = 0; i < 4; i++) {
                    int p = tid + i * 256;
                    int r = p >> 4, c4 = p & 15;
                    int gr = row0 + r;
                    aR[i] = (gr < M) ? *(const float4*)&Af[(long)gr * K + k1 + c4 * 4]
                                     : make_float4(0.f, 0.f, 0.f, 0.f);
                }
            }
#pragma unroll
            for (int i = 0; i < 4; i++) {
                int c = tid + i * 256;
                int n = c >> 3, koff = (c & 7) * 8;
                bR[i] = *(const bf16x8*)&Bt[(long)n * K + k1 + koff];
            }
        }

        bf16x8 af[2][2], bfr[2][4];
#pragma unroll
        for (int kk = 0; kk < 2; kk++) {
#pragma unroll
            for (int mi = 0; mi < 2; mi++)
                af[kk][mi] = *(const bf16x8*)&As[(m_off + mi * 16 + l16) * LDA2 + kk * 32 + quad * 8];
#pragma unroll
            for (int ni = 0; ni < 4; ni++)
                bfr[kk][ni] = *(const bf16x8*)&Bs[(n_off + ni * 16 + l16) * LDA2 + kk * 32 + quad * 8];
        }
#pragma unroll
        for (int kk = 0; kk < 2; kk++)
#pragma unroll
            for (int mi = 0; mi < 2; mi++)
#pragma unroll
                for (int ni = 0; ni < 4; ni++)
                    acc[mi][ni] = __builtin_amdgcn_mfma_f32_16x16x32_bf16(
                        af[kk][mi], bfr[kk][ni], acc[mi][ni], 0, 0, 0);
        __syncthreads();
    }

    // attention-vector partials for this lane's 4 cols
    float as_v[4], ad_v[4];
#pragma unroll
    for (int ni = 0; ni < 4; ni++) {
        int col = n_off + ni * 16 + l16;
        as_v[ni] = a_s[col];
        ad_v[ni] = a_d[col];
    }

    // epilogue: D row = m_off+mi*16+quad*4+r, col = n_off+ni*16+l16
#pragma unroll
    for (int mi = 0; mi < 2; mi++)
#pragma unroll
        for (int r = 0; r < 4; r++) {
            int row = row0 + m_off + mi * 16 + quad * 4 + r;
            float ps = 0.f, pd = 0.f;
#pragma unroll
            for (int ni = 0; ni < 4; ni++) {
                float v = acc[mi][ni][r];
                ps = fmaf(v, as_v[ni], ps);
                pd = fmaf(v, ad_v[ni], pd);
            }
#pragma unroll
            for (int o = 1; o < 16; o <<= 1) {
                ps += __shfl_xor(ps, o);
                pd += __shfl_xor(pd, o);
            }
            if (row < M) {
                if (l16 == 0) {
                    atomicAdd(es + row, ps);
                    atomicAdd(ed + row, pd);
                }
#pragma unroll
                for (int ni = 0; ni < 4; ni++) {
                    int col = n_off + ni * 16 + l16;
                    Cq[((long)(col >> 5) * N_NODES + row) * 32 + (col & 31)] =
                        f2bf(acc[mi][ni][r]);
                }
            }
        }
}

// ---------------- CSR build ----------------
__global__ void deg_hist(const int* __restrict__ ei, unsigned* __restrict__ deg) {
    int e = blockIdx.x * blockDim.x + threadIdx.x;
    if (e < N_EDGES) atomicAdd(&deg[ei[N_EDGES + e]], 1u);
}

// exclusive scan of (deg+1) -> row_ptr, fused with self-loop seed + cursor init.
__global__ __launch_bounds__(256) void scan_seed(const unsigned* __restrict__ deg,
                                                 unsigned* __restrict__ row_ptr,
                                                 unsigned* __restrict__ cursor,
                                                 unsigned* __restrict__ csr_src) {
    __shared__ unsigned psum_s[4];
    __shared__ unsigned wsum[4];
    int tid = threadIdx.x;
    int wid = tid >> 6, lane = tid & 63;
    int chunk0 = blockIdx.x * 256;

    unsigned psum = 0;
    for (int i = tid; i < chunk0; i += 256) psum += deg[i] + 1u;
    for (int o = 32; o; o >>= 1) psum += __shfl_xor(psum, o);
    if (lane == 0) psum_s[wid] = psum;

    int i = chunk0 + tid;
    unsigned v = (i < N_NODES) ? deg[i] + 1u : 0u;
    unsigned x = v;
    for (int o = 1; o < 64; o <<= 1) {
        unsigned y = __shfl_up(x, o);
        if (lane >= o) x += y;
    }
    if (lane == 63) wsum[wid] = x;
    __syncthreads();
    unsigned base = psum_s[0] + psum_s[1] + psum_s[2] + psum_s[3];
    unsigned wbase = 0;
    for (int k = 0; k < wid; k++) wbase += wsum[k];
    if (i < N_NODES) {
        unsigned rp = base + wbase + x - v;
        row_ptr[i] = rp;
        csr_src[rp] = (unsigned)i;   // self-loop first
        cursor[i] = rp + 1;
        if (i == N_NODES - 1) row_ptr[N_NODES] = rp + v;
    }
}

__global__ void csr_scatter(const int* __restrict__ ei,
                            unsigned* __restrict__ cursor, unsigned* __restrict__ csr_src) {
    int e = blockIdx.x * blockDim.x + threadIdx.x;
    if (e >= N_EDGES) return;
    int d = ei[N_EDGES + e];
    unsigned p = atomicAdd(&cursor[d], 1u);
    csr_src[p] = (unsigned)ei[e];
}

// ---------------- pass A: per-edge softmax weight alpha[slot] = exp(e)/den ----------------
// one node per half-wave (32 lanes); same-lane write-then-scale so no cross-lane visibility needed.
__global__ __launch_bounds__(256) void gat_alpha(
        const unsigned* __restrict__ row_ptr, const unsigned* __restrict__ csr_src,
        const float* __restrict__ e_src, const float* __restrict__ e_dst,
        float* __restrict__ alpha) {
    int hw = threadIdx.x >> 5;
    int node = blockIdx.x * 8 + hw;
    if (node >= N_NODES) return;
    int l = threadIdx.x & 31;
    unsigned beg = row_ptr[node], end = row_ptr[node + 1];
    int deg = (int)(end - beg);
    float ed = e_dst[node];
    float den = 0.f;

    if (deg <= 32) {
        float num = 0.f;
        if (l < deg) {
            unsigned s = csr_src[beg + l];
            float e = e_src[s] + ed;
            e = e > 0.f ? e : 0.2f * e;
            num = __expf(e);
            den = num;
        }
        for (int o = 16; o; o >>= 1) den += __shfl_xor(den, o);
        float inv = 1.f / den;
        if (l < deg) alpha[beg + l] = num * inv;
    } else {
        for (int base = 0; base < deg; base += 32) {
            int i = base + l;
            if (i < deg) {
                unsigned s = csr_src[beg + i];
                float e = e_src[s] + ed;
                e = e > 0.f ? e : 0.2f * e;
                float num = __expf(e);
                den += num;
                alpha[beg + i] = num;   // same lane rescales below
            }
        }
        for (int o = 16; o; o >>= 1) den += __shfl_xor(den, o);
        float inv = 1.f / den;
        for (int i = l; i < deg; i += 32) alpha[beg + i] *= inv;
    }
}

// ---------------- pass B: weighted gather over a 3.2 MB L2-resident quarter-table ----------------
// 1D grid, 12504 blocks (divisible by 8). Quarter q = (bid&7)>>1 pins each quarter to
// XCD pair {2q,2q+1} under the empirical bid%8->XCD round-robin (perf heuristic only).
// One node per 16-lane group; lane covers 2 features (uint = 2 bf16).
// xwq quarter-major: uint index (q*N_NODES + s)*16 + lane.
template<bool OUTBF16>
__global__ __launch_bounds__(256) void gat_gather(
        const unsigned* __restrict__ row_ptr, const unsigned* __restrict__ csr_src,
        const float* __restrict__ alpha, const unsigned* __restrict__ xwq,
        const float* __restrict__ bias, void* __restrict__ outv) {
    int bid = blockIdx.x;
    int xcd = bid & 7;
    int q   = xcd >> 1;                   // feature quarter 0..3
    int idx = (bid >> 3) * 2 + (xcd & 1); // within-quarter 16-node chunk
    if (idx * 16 >= N_NODES) return;
    int g = threadIdx.x >> 4;             // group 0..15
    int node = idx * 16 + g;
    if (node >= N_NODES) return;
    int l = threadIdx.x & 15;
    unsigned beg = row_ptr[node];
    int deg = (int)(row_ptr[node + 1] - beg);
    const unsigned* tbl = xwq + (long)q * N_NODES * 16 + l;

    float a0 = 0.f, a1 = 0.f;
    int t = 0;
    for (; t + 8 <= deg; t += 8) {
        unsigned s0 = csr_src[beg + t + 0]; float w0 = alpha[beg + t + 0];
        unsigned s1 = csr_src[beg + t + 1]; float w1 = alpha[beg + t + 1];
        unsigned s2 = csr_src[beg + t + 2]; float w2 = alpha[beg + t + 2];
        unsigned s3 = csr_src[beg + t + 3]; float w3 = alpha[beg + t + 3];
        unsigned s4 = csr_src[beg + t + 4]; float w4 = alpha[beg + t + 4];
        unsigned s5 = csr_src[beg + t + 5]; float w5 = alpha[beg + t + 5];
        unsigned s6 = csr_src[beg + t + 6]; float w6 = alpha[beg + t + 6];
        unsigned s7 = csr_src[beg + t + 7]; float w7 = alpha[beg + t + 7];
        unsigned u0 = tbl[(long)s0 * 16];
        unsigned u1 = tbl[(long)s1 * 16];
        unsigned u2 = tbl[(long)s2 * 16];
        unsigned u3 = tbl[(long)s3 * 16];
        unsigned u4 = tbl[(long)s4 * 16];
        unsigned u5 = tbl[(long)s5 * 16];
        unsigned u6 = tbl[(long)s6 * 16];
        unsigned u7 = tbl[(long)s7 * 16];
        a0 = fmaf(w0, bflo(u0), a0); a1 = fmaf(w0, bfhi(u0), a1);
        a0 = fmaf(w1, bflo(u1), a0); a1 = fmaf(w1, bfhi(u1), a1);
        a0 = fmaf(w2, bflo(u2), a0); a1 = fmaf(w2, bfhi(u2), a1);
        a0 = fmaf(w3, bflo(u3), a0); a1 = fmaf(w3, bfhi(u3), a1);
        a0 = fmaf(w4, bflo(u4), a0); a1 = fmaf(w4, bfhi(u4), a1);
        a0 = fmaf(w5, bflo(u5), a0); a1 = fmaf(w5, bfhi(u5), a1);
        a0 = fmaf(w6, bflo(u6), a0); a1 = fmaf(w6, bfhi(u6), a1);
        a0 = fmaf(w7, bflo(u7), a0); a1 = fmaf(w7, bfhi(u7), a1);
    }
    for (; t < deg; t++) {
        unsigned s = csr_src[beg + t]; float w = alpha[beg + t];
        unsigned u = tbl[(long)s * 16];
        a0 = fmaf(w, bflo(u), a0); a1 = fmaf(w, bfhi(u), a1);
    }

    float2 b = *(const float2*)&bias[q * 32 + l * 2];
    float v0 = selu_f(a0 + b.x);
    float v1 = selu_f(a1 + b.y);
    if (OUTBF16) {
        unsigned o = ((unsigned)f2bf(v1) << 16) | (unsigned)f2bf(v0);
        *((unsigned*)outv + (long)node * 64 + q * 16 + l) = o;   // row-major bf16 [node][128]
    } else {
        float2 o = make_float2(v0, v1);
        *(float2*)((float*)outv + (long)node * HID2 + q * 32 + l * 2) = o;
    }
}

// ---------------- fused pool + fc1 + fc2 + log_softmax: one block per graph ----------------
__global__ __launch_bounds__(256) void pool_head(
        const float* __restrict__ h, const int* __restrict__ batch,
        const float* __restrict__ fc1w, const float* __restrict__ fc1b,
        const float* __restrict__ fc2w, const float* __restrict__ fc2b,
        float* __restrict__ out) {
    __shared__ float pooled_s[HID2];
    __shared__ float part[HID2];
    __shared__ float g_s[NHID];
    int g = blockIdx.x;
    int lo = 0, hi = N_NODES;
    while (lo < hi) { int mid = (lo + hi) >> 1; if (batch[mid] < g) lo = mid + 1; else hi = mid; }
    int start = lo;
    hi = N_NODES;
    while (lo < hi) { int mid = (lo + hi) >> 1; if (batch[mid] < g + 1) lo = mid + 1; else hi = mid; }
    int end = lo;

    int f = threadIdx.x & 127, half = threadIdx.x >> 7;
    float acc = 0.f;
    for (int n = start + half; n < end; n += 2) acc += h[(long)n * HID2 + f];
    if (half == 0) part[f] = acc;
    __syncthreads();
    if (half == 1) {
        float c = (float)(end - start);
        c = c > 1.f ? c : 1.f;
        pooled_s[f] = selu_f((part[f] + acc) / c);
    }
    __syncthreads();
    int j = threadIdx.x;
    if (j < NHID) {
        float a = fc1b[j];
#pragma unroll
        for (int k = 0; k < HID2; k++) a = fmaf(pooled_s[k], fc1w[k * NHID + j], a);
        g_s[j] = selu_f(a);
    }
    __syncthreads();
    if (j == 0) {
        float l0 = fc2b[0], l1 = fc2b[1];
#pragma unroll
        for (int k = 0; k < NHID; k++) {
            float v = g_s[k];
            l0 = fmaf(v, fc2w[2 * k + 0], l0);
            l1 = fmaf(v, fc2w[2 * k + 1], l1);
        }
        float m = fmaxf(l0, l1);
        float lse = m + logf(expf(l0 - m) + expf(l1 - m));
        out[g * 2 + 0] = l0 - lse;
        out[g * 2 + 1] = l1 - lse;
    }
}

extern "C" void kernel_launch(void* const* d_in, const int* in_sizes, int n_in,
                              void* d_out, int out_size, void* d_ws, size_t ws_size,
                              hipStream_t stream) {
    const float* x     = (const float*)d_in[0];
    const int*   ei    = (const int*)d_in[1];
    const int*   batch = (const int*)d_in[2];
    const float* W1    = (const float*)d_in[3];
    const float* as1   = (const float*)d_in[4];
    const float* ad1   = (const float*)d_in[5];
    const float* b1    = (const float*)d_in[6];
    const float* W2    = (const float*)d_in[7];
    const float* as2   = (const float*)d_in[8];
    const float* ad2   = (const float*)d_in[9];
    const float* b2    = (const float*)d_in[10];
    const float* fc1w  = (const float*)d_in[11];
    const float* fc1b  = (const float*)d_in[12];
    const float* fc2w  = (const float*)d_in[13];
    const float* fc2b  = (const float*)d_in[14];
    float* out = (float*)d_out;

    // workspace layout
    const long NH = (long)N_NODES * HID2;        // 6.4M elems
    unsigned short* xwb = (unsigned short*)d_ws;         // NH bf16 (xw, quarter-major, both layers)
    unsigned short* h1b = xwb + NH;                      // NH bf16 (h1, row-major)
    float*    B2      = (float*)(h1b + NH);              // NH f32 (h2, row-major, for pooling)
    float*    es1     = B2 + NH;
    float*    ed1     = es1 + N_NODES;
    float*    es2     = ed1 + N_NODES;
    float*    ed2     = es2 + N_NODES;
    unsigned* deg     = (unsigned*)(ed2 + N_NODES);
    unsigned* cursor  = deg + N_NODES;
    unsigned* row_ptr = cursor + N_NODES;               // N_NODES+1
    unsigned* csr_src = row_ptr + N_NODES + 1;          // E_TOT
    unsigned short* Wt1 = (unsigned short*)(csr_src + E_TOT);  // 128x768 bf16
    unsigned short* Wt2 = Wt1 + 128 * IN_F;                    // 128x128 bf16
    float*    alphaB  = (float*)(Wt2 + 128 * HID2);            // E_TOT f32

    const int TB = 256;
    const int gNode = (N_NODES + TB - 1) / TB;
    const int gEdge = (N_EDGES + TB - 1) / TB;
    const int gGemm = (N_NODES + 63) / 64;
    const int gAlpha = (N_NODES + 7) / 8;
    const int gGather = 12504;   // 8 * 1563; per quarter: 1563*2=3126 chunks >= 3125 needed

    // setup (zero deg + e-buffers, weight converts) + CSR build
    setup_k<<<(128 * IN_F + TB - 1) / TB, TB, 0, stream>>>(W1, W2, Wt1, Wt2, deg,
                                                           es1, ed1, es2, ed2);
    deg_hist<<<gEdge, TB, 0, stream>>>(ei, deg);
    scan_seed<<<gNode, TB, 0, stream>>>(deg, row_ptr, cursor, csr_src);
    csr_scatter<<<gEdge, TB, 0, stream>>>(ei, cursor, csr_src);

    // ---- layer 1 ----
    gemm_mfma<false><<<gGemm, 256, 0, stream>>>(x, Wt1, xwb, N_NODES, IN_F,
                                                as1, ad1, es1, ed1);
    gat_alpha<<<gAlpha, TB, 0, stream>>>(row_ptr, csr_src, es1, ed1, alphaB);
    gat_gather<true><<<gGather, TB, 0, stream>>>(row_ptr, csr_src, alphaB,
                                                 (const unsigned*)xwb, b1, h1b);

    // ---- layer 2 ----
    gemm_mfma<true><<<gGemm, 256, 0, stream>>>(h1b, Wt2, xwb, N_NODES, HID2,
                                               as2, ad2, es2, ed2);
    gat_alpha<<<gAlpha, TB, 0, stream>>>(row_ptr, csr_src, es2, ed2, alphaB);
    gat_gather<false><<<gGather, TB, 0, stream>>>(row_ptr, csr_src, alphaB,
                                                  (const unsigned*)xwb, b2, B2);

    // ---- pool + head (fused) ----
    pool_head<<<N_GRAPHS, 256, 0, stream>>>(B2, batch, fc1w, fc1b, fc2w, fc2b, out);
}